// Round 3
// baseline (332.971 us; speedup 1.0000x reference)
//
#include <hip/hip_runtime.h>

#define NPHI 64
#define NS 8
#define NK 16
#define BATCH 512

// In-place Gauss-Jordan (sweep-operator) inversion of an 8x8 complex matrix
// held one element per lane of wave 0 (lane = i*8+j). No pivoting: HPD input.
__device__ __forceinline__ void cinv8(float& ar, float& ai, int lane) {
    const int i = lane >> 3, j = lane & 7;
#pragma unroll
    for (int p = 0; p < 8; ++p) {
        const float pr = __shfl(ar, p * 9, 64);
        const float pi = __shfl(ai, p * 9, 64);
        const float den = pr * pr + pi * pi;
        const float rr = pr / den, ri = -pi / den;           // r = 1/pivot
        const float aipr = __shfl(ar, (i << 3) | p, 64);
        const float aipi = __shfl(ai, (i << 3) | p, 64);
        const float apjr = __shfl(ar, (p << 3) | j, 64);
        const float apji = __shfl(ai, (p << 3) | j, 64);
        // b = r * a[p][j]  (new pivot-row value)
        const float br = rr * apjr - ri * apji;
        const float bi = rr * apji + ri * apjr;
        // general elimination: own - a[i][p]_old * (r*a[p][j]_old)
        const float er = ar - (aipr * br - aipi * bi);
        const float ei = ai - (aipr * bi + aipi * br);
        // pivot row (r*own) / pivot column (-r*own)
        const float rowr = rr * ar - ri * ai;
        const float rowi = rr * ai + ri * ar;
        const bool ip = (i == p), jp = (j == p);
        const float nr = ip ? (jp ? rr : rowr) : (jp ? -rowr : er);
        const float ni = ip ? (jp ? ri : rowi) : (jp ? -rowi : ei);
        ar = nr; ai = ni;
    }
}

// One block per (k,b). Computes d[k,b,f] = (G_h[f,:] @ Qi^2 @ T[:,f]) / beta
// where T = (G Phi) C, Q = inv(Lam) + T M^H / beta, M = G Phi.
// Result staged into the FRONT of batch-b's own output region (region floats):
//   out[b*region + k*128 + 2*f (+1)]  -- overwritten later by k_finalize(b).
__global__ __launch_bounds__(256, 2) void k_grad_diag(
    const float* __restrict__ PhiR, const float* __restrict__ PhiI,
    const float* __restrict__ GhR, const float* __restrict__ GhI,
    const float* __restrict__ LamR, const float* __restrict__ LamI,
    const float* __restrict__ CR, const float* __restrict__ CI,
    const float* __restrict__ Beta,
    float* __restrict__ out, int region)
{
    const int bid = blockIdx.x;
    const int k = bid & (NK - 1);
    const int b = bid >> 4;
    const int tid = threadIdx.x;
    const int lane = tid & 63;   // column (f or g)
    const int part = tid >> 6;   // depth quarter (wave id)

    __shared__ float2 sPart[4][512];              // partials [part][s*64+col] 16 KB
    __shared__ __align__(16) float2 sM[NPHI][10]; // M^T [f][s], 80B rows      5 KB
    __shared__ float2 sT[NS][NPHI];               // T [s][g]                  4 KB
    __shared__ float2 sS[64];                     // S = T M^H / beta
    __shared__ float2 sQ2[64];                    // Qi^2

    const float* phiR = PhiR + b * 4096;
    const float* phiI = PhiI + b * 4096;
    const int kb = k * BATCH + b;
    const float* ghR = GhR + kb * 512;
    const float* ghI = GhI + kb * 512;
    const float invb = 1.0f / Beta[kb];

    // ---- M[s,f] = sum_e conj(gh[e,s]) * phi[e,f] ; thread=(f=lane, e-quarter=part)
    {
        float mr[8], mi[8];
#pragma unroll
        for (int s = 0; s < 8; ++s) { mr[s] = 0.f; mi[s] = 0.f; }
#pragma unroll
        for (int ee = 0; ee < 16; ++ee) {
            const int e = part * 16 + ee;
            const float pr = phiR[e * 64 + lane];
            const float pi = phiI[e * 64 + lane];
            const float4 g0 = *(const float4*)(ghR + e * 8);
            const float4 g1 = *(const float4*)(ghR + e * 8 + 4);
            const float4 h0 = *(const float4*)(ghI + e * 8);
            const float4 h1 = *(const float4*)(ghI + e * 8 + 4);
            const float gr[8] = {g0.x, g0.y, g0.z, g0.w, g1.x, g1.y, g1.z, g1.w};
            const float gi[8] = {h0.x, h0.y, h0.z, h0.w, h1.x, h1.y, h1.z, h1.w};
#pragma unroll
            for (int s = 0; s < 8; ++s) {
                mr[s] += gr[s] * pr + gi[s] * pi;   // conj(g)*p
                mi[s] += gr[s] * pi - gi[s] * pr;
            }
        }
#pragma unroll
        for (int s = 0; s < 8; ++s) sPart[part][s * 64 + lane] = make_float2(mr[s], mi[s]);
    }
    __syncthreads();
    for (int o = tid; o < 512; o += 256) {
        const float2 a0 = sPart[0][o], a1 = sPart[1][o], a2 = sPart[2][o], a3 = sPart[3][o];
        sM[o & 63][o >> 6] = make_float2((a0.x + a1.x) + (a2.x + a3.x),
                                         (a0.y + a1.y) + (a2.y + a3.y));
    }
    __syncthreads();

    // ---- T[s,g] = sum_f M[s,f]*C[f,g] ; thread=(g=lane, f-quarter=part). C read once, coalesced.
    {
        const float* cR = CR + (size_t)kb * 4096;
        const float* cI = CI + (size_t)kb * 4096;
        float tr[8], ti[8];
#pragma unroll
        for (int s = 0; s < 8; ++s) { tr[s] = 0.f; ti[s] = 0.f; }
#pragma unroll
        for (int ff = 0; ff < 16; ++ff) {
            const int f = part * 16 + ff;
            const float cr = cR[f * 64 + lane];
            const float ci = cI[f * 64 + lane];
            const float4* mrow = (const float4*)(&sM[f][0]);  // broadcast reads
            const float4 q0 = mrow[0], q1 = mrow[1], q2 = mrow[2], q3 = mrow[3];
            tr[0] += q0.x * cr - q0.y * ci;  ti[0] += q0.x * ci + q0.y * cr;
            tr[1] += q0.z * cr - q0.w * ci;  ti[1] += q0.z * ci + q0.w * cr;
            tr[2] += q1.x * cr - q1.y * ci;  ti[2] += q1.x * ci + q1.y * cr;
            tr[3] += q1.z * cr - q1.w * ci;  ti[3] += q1.z * ci + q1.w * cr;
            tr[4] += q2.x * cr - q2.y * ci;  ti[4] += q2.x * ci + q2.y * cr;
            tr[5] += q2.z * cr - q2.w * ci;  ti[5] += q2.z * ci + q2.w * cr;
            tr[6] += q3.x * cr - q3.y * ci;  ti[6] += q3.x * ci + q3.y * cr;
            tr[7] += q3.z * cr - q3.w * ci;  ti[7] += q3.z * ci + q3.w * cr;
        }
#pragma unroll
        for (int s = 0; s < 8; ++s) sPart[part][s * 64 + lane] = make_float2(tr[s], ti[s]);
    }
    __syncthreads();
    for (int o = tid; o < 512; o += 256) {
        const float2 a0 = sPart[0][o], a1 = sPart[1][o], a2 = sPart[2][o], a3 = sPart[3][o];
        sT[o >> 6][o & 63] = make_float2((a0.x + a1.x) + (a2.x + a3.x),
                                         (a0.y + a1.y) + (a2.y + a3.y));
    }
    __syncthreads();

    // ---- S[s,t] = (sum_g T[s,g]*conj(M[t,g])) / beta ; 4 threads per output
    {
        const int o = tid >> 2;
        const int si = o >> 3, tj = o & 7, pq = tid & 3;
        float sre = 0.f, sim = 0.f;
#pragma unroll
        for (int gg = 0; gg < 16; ++gg) {
            const int g = pq * 16 + gg;
            const float2 tv = sT[si][g];
            const float2 mv = sM[g][tj];
            sre += tv.x * mv.x + tv.y * mv.y;   // T * conj(M)
            sim += tv.y * mv.x - tv.x * mv.y;
        }
        sre += __shfl_xor(sre, 1, 64); sim += __shfl_xor(sim, 1, 64);
        sre += __shfl_xor(sre, 2, 64); sim += __shfl_xor(sim, 2, 64);
        if (pq == 0) sS[o] = make_float2(sre * invb, sim * invb);
    }
    __syncthreads();

    // ---- Q = inv(Lam) + S ; Qi = inv(Q); Qi2 = Qi@Qi  (wave 0, lane = i*8+j)
    if (tid < 64) {
        float ar = LamR[kb * 64 + tid];
        float ai = LamI[kb * 64 + tid];
        cinv8(ar, ai, tid);
        const float2 sv = sS[tid];
        ar += sv.x; ai += sv.y;
        cinv8(ar, ai, tid);
        const int i = tid >> 3, j = tid & 7;
        float qr = 0.f, qi = 0.f;
#pragma unroll
        for (int t = 0; t < 8; ++t) {
            const float xr = __shfl(ar, (i << 3) | t, 64);
            const float xi = __shfl(ai, (i << 3) | t, 64);
            const float yr = __shfl(ar, (t << 3) | j, 64);
            const float yi = __shfl(ai, (t << 3) | j, 64);
            qr += xr * yr - xi * yi;
            qi += xr * yi + xi * yr;
        }
        sQ2[tid] = make_float2(qr, qi);
    }
    __syncthreads();

    // ---- d[f] = (sum_s gh[f,s] * sum_t Qi2[s,t]*T[t,f]) / beta ; 4 threads/f
    {
        const int f = tid >> 2, pq = tid & 3;
        float dre = 0.f, dim = 0.f;
#pragma unroll
        for (int ss = 0; ss < 2; ++ss) {
            const int s = pq * 2 + ss;
            float yr = 0.f, yi = 0.f;
#pragma unroll
            for (int t = 0; t < 8; ++t) {
                const float2 q = sQ2[s * 8 + t];
                const float2 tv = sT[t][f];
                yr += q.x * tv.x - q.y * tv.y;
                yi += q.x * tv.y + q.y * tv.x;
            }
            const float gr = ghR[f * 8 + s];
            const float gi = ghI[f * 8 + s];
            dre += gr * yr - gi * yi;
            dim += gr * yi + gi * yr;
        }
        dre += __shfl_xor(dre, 1, 64); dim += __shfl_xor(dim, 1, 64);
        dre += __shfl_xor(dre, 2, 64); dim += __shfl_xor(dim, 2, 64);
        if (pq == 0) {
            float2* scr = (float2*)(out + (size_t)b * region + k * 128);
            scr[f] = make_float2(dre * invb, dim * invb);
        }
    }
}

// One block per b: step-size NN, diagonal Riemannian update, clamp, store.
// Reads own-region scratch (front 2048 floats) before overwriting the region.
__global__ __launch_bounds__(256) void k_finalize(
    const float* __restrict__ PhiR, const float* __restrict__ PhiI,
    const float* __restrict__ bnG, const float* __restrict__ bnB,
    const float* __restrict__ bnM, const float* __restrict__ bnV,
    const float* __restrict__ W, const float* __restrict__ Bb,
    float* __restrict__ out, int region, int cplx)
{
    const int b = blockIdx.x;
    const int tid = threadIdx.x;
    __shared__ float sIQ[128];
    __shared__ float sRed[2];
    __shared__ float sDre[64], sDim[64];

    const float* phiR = PhiR + b * 4096;
    const float* phiI = PhiI + b * 4096;
    float* outp = out + (size_t)b * region;

    // diagonal eg sum over k from own-region scratch (read BEFORE any writes)
    float er = 0.f, ei = 0.f;
    if (tid < 64) {
        const int f = tid;
#pragma unroll
        for (int kk = 0; kk < NK; ++kk) {
            const float2 dv = ((const float2*)(outp + kk * 128))[f];
            er += dv.x; ei += dv.y;
        }
    }

    // row sums of Phi (Phi @ ones): 4 threads per row
    {
        const int r = tid >> 2, pq = tid & 3;
        float sr = 0.f, si = 0.f;
        const float4* a4 = (const float4*)(phiR + r * 64 + pq * 16);
        const float4* c4 = (const float4*)(phiI + r * 64 + pq * 16);
#pragma unroll
        for (int q = 0; q < 4; ++q) {
            const float4 a = a4[q]; sr += (a.x + a.y) + (a.z + a.w);
            const float4 c = c4[q]; si += (c.x + c.y) + (c.z + c.w);
        }
        sr += __shfl_xor(sr, 1, 64); si += __shfl_xor(si, 1, 64);
        sr += __shfl_xor(sr, 2, 64); si += __shfl_xor(si, 2, 64);
        if (pq == 0) { sIQ[r] = sr; sIQ[64 + r] = si; }
    }
    __syncthreads();

    // BN -> Dense(1) -> leaky_relu
    if (tid < 128) {
        const float v = sIQ[tid];
        const float t = bnG[tid] * (v - bnM[tid]) * rsqrtf(bnV[tid] + 1e-3f) + bnB[tid];
        float contrib = t * W[tid];
#pragma unroll
        for (int o = 1; o < 64; o <<= 1) contrib += __shfl_xor(contrib, o, 64);
        if ((tid & 63) == 0) sRed[tid >> 6] = contrib;
    }
    __syncthreads();
    const float s_lin = sRed[0] + sRed[1] + Bb[0];
    const float step = (s_lin >= 0.f) ? s_lin : 0.1f * s_lin;

    // diagonal Riemannian gradient + norm (rg is exactly 0 off-diagonal)
    if (tid < 64) {
        const int f = tid;
        er *= -(1.0f / NK); ei *= -(1.0f / NK);
        const float prr = phiR[f * 65];
        const float pii = phiI[f * 65];
        const float proj = er * prr + ei * pii;     // Re(eg * conj(Phi))
        const float rr = er - proj * prr;
        const float ri = ei - proj * pii;
        float n2 = rr * rr + ri * ri;
#pragma unroll
        for (int o = 1; o < 64; o <<= 1) n2 += __shfl_xor(n2, o, 64);
        const float sc = step / sqrtf(n2);
        sDre[f] = sc * rr;
        sDim[f] = sc * ri;
    }
    __syncthreads();   // all scratch reads done; safe to overwrite region

    // elementwise: subtract diag update, magnitude clamp, store
#pragma unroll
    for (int p = 0; p < 4; ++p) {
        const int base = p * 1024 + tid * 4;
        const float4 a = *(const float4*)(phiR + base);
        const float4 c = *(const float4*)(phiI + base);
        const int row = base >> 6;
        const int col0 = base & 63;
        float re[4] = {a.x, a.y, a.z, a.w};
        float im[4] = {c.x, c.y, c.z, c.w};
#pragma unroll
        for (int q = 0; q < 4; ++q) {
            if (row == col0 + q) { re[q] -= sDre[row]; im[q] -= sDim[row]; }
            const float ab = sqrtf(re[q] * re[q] + im[q] * im[q]);
            const float den = fmaxf(ab - 1.f, 0.f) + 1.f;
            re[q] /= den; im[q] /= den;
        }
        if (cplx) {
            *(float4*)(outp + base * 2)     = make_float4(re[0], im[0], re[1], im[1]);
            *(float4*)(outp + base * 2 + 4) = make_float4(re[2], im[2], re[3], im[3]);
        } else {
            *(float4*)(outp + base) = make_float4(re[0], re[1], re[2], re[3]);
        }
    }
}

extern "C" void kernel_launch(void* const* d_in, const int* in_sizes, int n_in,
                              void* d_out, int out_size, void* d_ws, size_t ws_size,
                              hipStream_t stream) {
    const float* PhiR = (const float*)d_in[0];
    const float* PhiI = (const float*)d_in[1];
    const float* GhR  = (const float*)d_in[2];
    const float* GhI  = (const float*)d_in[3];
    const float* LamR = (const float*)d_in[4];
    const float* LamI = (const float*)d_in[5];
    const float* CR   = (const float*)d_in[6];
    const float* CI   = (const float*)d_in[7];
    const float* Beta = (const float*)d_in[8];
    const float* bnG  = (const float*)d_in[9];
    const float* bnB  = (const float*)d_in[10];
    const float* bnM  = (const float*)d_in[11];
    const float* bnV  = (const float*)d_in[12];
    const float* W    = (const float*)d_in[13];
    const float* Bb   = (const float*)d_in[14];
    float* outp = (float*)d_out;

    // out_size == B*64*64 (2,097,152)  -> real-part-only float32 layout
    // out_size == B*64*64*2            -> interleaved complex64 layout
    const int cplx = (out_size >= 3000000) ? 1 : 0;
    const int region = cplx ? 8192 : 4096;

    k_grad_diag<<<NK * BATCH, 256, 0, stream>>>(PhiR, PhiI, GhR, GhI,
                                                LamR, LamI, CR, CI, Beta,
                                                outp, region);
    k_finalize<<<BATCH, 256, 0, stream>>>(PhiR, PhiI,
                                          bnG, bnB, bnM, bnV, W, Bb,
                                          outp, region, cplx);
}